// Round 13
// baseline (226.791 us; speedup 1.0000x reference)
//
#include <hip/hip_runtime.h>
#include <stdint.h>

// out[p,b,o] = sum_i x*w0 + (1-x)*w1 = sum_i x*(w0-w1) + sum_i w1
// R21: COMPRESS-THEN-DUPLICATE. The uncompressed w stream can't be both
// no-dup and 1024B-strip (R15/R16 ladder) and cross-block sharing failed 4
// ways (R17-R20). So: pack_w reads w PERFECTLY LINEARLY (4 consecutive
// k-rows = 32KB contiguous per block) and emits 2-bit codes (R20's
// absmax-0-verified format: bit 2*(4c+j) pair = w0bit | w1bit<<1) in the
// exact word layout the GEMM consumes. evo_code = R16 skeleton with the w
// stream replaced by code words (16 MiB total; per-tile slice 128KB ->
// L2-resident for both row-half blocks regardless of drift -> duplication
// is FREE). colsum(w1) falls out of DECODE's hi-bit popc (R20-verified).
//   pack_w: grid 8192 = 16p x 512 kq, 256 thr, 8KB LDS combine.
//   evo_code: grid 256 = (t = p*8+og, 256 cols) x (h = b-half), 512 thr,
//   R16 acc/epilogue verbatim, 1-step code prefetch, lgkm-only barriers.
// Fallback: verbatim R16 (162.6us) if ws < 18.87 MB (R20 proved it isn't).

#define NP 16
#define NB 512
#define NI 2048
#define NO 2048
#define JW 64               // u32 words per i-row in xp
#define OT 256              // o-columns per tile
#define KS 32               // k-rows per step
#define CBT 32768           // code words per tile (64 steps x 512 thr)
#define XP_WORDS (NP * NB * JW)   // 524288 u32 = 2 MiB

typedef __attribute__((ext_vector_type(8))) short short8;
typedef __attribute__((ext_vector_type(4))) float f32x4;

__global__ __launch_bounds__(256) void pack_x_kernel(const float* __restrict__ x,
                                                     uint32_t* __restrict__ xp) {
    const int gtid = blockIdx.x * 256 + threadIdx.x;
    const int row  = gtid >> 6;     // p*NB + b
    const int lane = gtid & 63;
    const float* src = x + (size_t)row * NI;
    unsigned long long* dst = (unsigned long long*)(xp + (size_t)row * JW);
#pragma unroll 4
    for (int k = 0; k < NI / 64; ++k) {
        const float v = src[k * 64 + lane];
        const unsigned long long m = __ballot(v != 0.0f);
        if (lane == 0) dst[k] = m;
    }
}

// ---- pack_w: linear 512 MiB sweep -> 16 MiB codes in evo word layout ----
// Block (p, kq): reads k-rows 4kq..4kq+3 (32KB contiguous) of w0 and w1.
// Word for col-group c4 (cols 4c4..+3), k-group kq: bit 2*(4c'+j) pair.
// Written at cb[((p*8+og)*64 + s)*512 + wvq*64 + ln] with og=c4>>6,
// s=kq>>3, wvq=kq&7, ln=c4&63  (== evo's cbp[s*512 + wv*64 + lane]).
__global__ __launch_bounds__(256) void pack_w_kernel(const float* __restrict__ w,
                                                     uint32_t* __restrict__ cb) {
    __shared__ uint32_t pl[4][512];   // 8 KB: per-k-row partial words

    const int tid = threadIdx.x;
    const int bid = blockIdx.x;       // p*512 + kq
    const int p   = bid >> 9;
    const int kq  = bid & 511;

    const float* w0 = w + (size_t)p * ((size_t)NI * NO) + (size_t)kq * 4 * NO;
    const float* w1 = w0 + (size_t)NP * NI * NO;

#pragma unroll
    for (int ph = 0; ph < 8; ++ph) {
        const int g  = 256 * ph + tid;        // f32x4 index in 4x2048 tile
        const int j  = ph >> 1;               // k-row 0..3 (compile-time)
        const int c4 = (ph & 1) * 256 + tid;  // col-group 0..511
        const f32x4 a = *(const f32x4*)(w0 + 4 * (size_t)g);
        const f32x4 b = *(const f32x4*)(w1 + 4 * (size_t)g);
        uint32_t pw = 0;
#pragma unroll
        for (int e = 0; e < 4; ++e)
            pw |= (((__float_as_uint(a[e]) >> 23) & 1u)
                 | ((__float_as_uint(b[e]) >> 22) & 2u)) << (8 * e + 2 * j);
        pl[j][c4] = pw;
    }
    __syncthreads();

#pragma unroll
    for (int q = 0; q < 2; ++q) {
        const int c4 = q * 256 + tid;
        const uint32_t wd = pl[0][c4] | pl[1][c4] | pl[2][c4] | pl[3][c4];
        const int og = c4 >> 6, ln = c4 & 63;
        cb[((size_t)(p * 8 + og) * 64 + (kq >> 3)) * 512 + (kq & 7) * 64 + ln] = wd;
    }
}

// ---------------------------------------------------------- shared macros ----
#define BF16(f) ((uint32_t)(__float_as_uint(f) >> 16))

// (fallback only) issue next step's w: k-rows 4wv..+3, lane cols 4l..4l+3
#define WISS(s0_, s1_) do {                                                    \
    _Pragma("unroll")                                                          \
    for (int _j = 0; _j < 4; ++_j) {                                           \
        s0_[_j] = *(const f32x4*)(w0n + (size_t)_j * NO);                      \
        s1_[_j] = *(const f32x4*)(w1n + (size_t)_j * NO);                      \
    }                                                                          \
    w0n += (size_t)KS * NO; w1n += (size_t)KS * NO;                            \
} while (0)

// (fallback only) convert w regs -> bf16 d tile rows 4wv..+3; colsum(w1)
#define CVT(s0_, s1_, b_) do {                                                 \
    _Pragma("unroll")                                                          \
    for (int _c = 0; _c < 4; ++_c) {                                           \
        const float _d0 = s0_[0][_c] - s1_[0][_c];                             \
        const float _d1 = s0_[1][_c] - s1_[1][_c];                             \
        const float _d2 = s0_[2][_c] - s1_[2][_c];                             \
        const float _d3 = s0_[3][_c] - s1_[3][_c];                             \
        cs[_c] += s1_[0][_c] + s1_[1][_c] + s1_[2][_c] + s1_[3][_c];           \
        uint2 _st;                                                             \
        _st.x = BF16(_d0) | (BF16(_d1) << 16);                                 \
        _st.y = BF16(_d2) | (BF16(_d3) << 16);                                 \
        *(uint2*)&bds[b_][4 * lane + _c][4 * wv] = _st;                        \
    }                                                                          \
} while (0)

// decode one code word -> bf16 d rows 4wv..+3 of bds[b_]; colsum from hi bits
#define DEC1(cx) ((((cx) & 3u) == 1u) ? 0x3F80u                                \
                  : ((((cx) & 3u) == 2u) ? 0xBF80u : 0u))
#define DECODE(cw_, b_) do {                                                   \
    _Pragma("unroll")                                                          \
    for (int _c = 0; _c < 4; ++_c) {                                           \
        uint2 _st;                                                             \
        _st.x = DEC1((cw_) >> (8 * _c))     | (DEC1((cw_) >> (8 * _c + 2)) << 16); \
        _st.y = DEC1((cw_) >> (8 * _c + 4)) | (DEC1((cw_) >> (8 * _c + 6)) << 16); \
        cs[_c] += (float)__popc((cw_) & (0xAAu << (8 * _c)));                  \
        *(uint2*)&bds[b_][4 * lane + _c][4 * wv] = _st;                        \
    }                                                                          \
} while (0)

// issue next x words (2 m-frag rows' step-word) and bump
#define XISS(xw) do {                                                          \
    xw[0] = xn[0]; xw[1] = xn[1024];                                           \
    xn += 1;                                                                   \
} while (0)

// expand A-frags from packed-x words: bit -> bf16 {0,1}  (R14-verified)
#define AEXP(afr, xw) do {                                                     \
    _Pragma("unroll")                                                          \
    for (int _mi = 0; _mi < 2; ++_mi) {                                        \
        const uint32_t _by = (xw[_mi] >> klo8) & 0xFFu;                        \
        union { uint32_t u[4]; short8 s; } _cv;                                \
        _cv.u[0] = (_by & 1u   ? 0x3F80u : 0u) | (_by & 2u   ? 0x3F800000u : 0u); \
        _cv.u[1] = (_by & 4u   ? 0x3F80u : 0u) | (_by & 8u   ? 0x3F800000u : 0u); \
        _cv.u[2] = (_by & 16u  ? 0x3F80u : 0u) | (_by & 32u  ? 0x3F800000u : 0u); \
        _cv.u[3] = (_by & 64u  ? 0x3F80u : 0u) | (_by & 128u ? 0x3F800000u : 0u); \
        afr[_mi] = _cv.s;                                                      \
    }                                                                          \
} while (0)

// read B-frags from bds[b_] (two b64s each; pitch 88B) + 2m x 16n MFMA
#define BRDMFMA(afr, b_) do {                                                  \
    _Pragma("unroll")                                                          \
    for (int _nj = 0; _nj < 16; ++_nj) {                                       \
        union { uint2 q[2]; short8 s; } _u;                                    \
        _u.q[0] = *(const uint2*)&bds[b_][_nj * 16 + lanelo][klo8];            \
        _u.q[1] = *(const uint2*)&bds[b_][_nj * 16 + lanelo][klo8 + 4];        \
        _Pragma("unroll")                                                      \
        for (int _mi = 0; _mi < 2; ++_mi)                                      \
            acc[_mi][_nj] = __builtin_amdgcn_mfma_f32_16x16x32_bf16(           \
                afr[_mi], _u.s, acc[_mi][_nj], 0, 0, 0);                       \
    }                                                                          \
} while (0)

// lgkmcnt-only barrier: LDS visibility without draining the vmcnt FIFO
#define BARLDS() asm volatile("s_waitcnt lgkmcnt(0)\n\ts_barrier" ::: "memory")

// ------------------------------------------------------ evo from codes ----
__global__ __launch_bounds__(512, 2) void evo_code(const uint32_t* __restrict__ cb,
                                                   const uint32_t* __restrict__ xp,
                                                   float* __restrict__ out) {
    __shared__ __align__(16) uint16_t bds[2][OT][44];  // 44 KB, dbuf d tile
    __shared__ float csl[8][64][4];                    // 8 KB, colsum partials

    const int tid    = threadIdx.x;
    const int lane   = tid & 63;
    const int wv     = __builtin_amdgcn_readfirstlane(tid >> 6);  // 0..7
    const int lanelo = lane & 15;
    const int klo8   = (lane >> 4) * 8;
    const int h      = blockIdx.x >> 7;   // b-half 0..1
    const int t      = blockIdx.x & 127;  // tile (both halves share codes)
    const int p      = t >> 3;            // 0..15
    const int og     = t & 7;             // 0..7

    const uint32_t* xn  = xp + ((size_t)p * NB + h * 256 + wv * 32 + lanelo) * JW;
    const uint32_t* cbp = cb + (size_t)t * CBT + tid;

    f32x4 acc[2][16];
#pragma unroll
    for (int mi = 0; mi < 2; ++mi)
#pragma unroll
        for (int nj = 0; nj < 16; ++nj) acc[mi][nj] = (f32x4)0.0f;
    float cs[4] = {0.0f, 0.0f, 0.0f, 0.0f};

    uint32_t xwA[2], xwB[2], cwA, cwB;

    // ---- prologue: codes(0),(1) + x(0),(1) in flight; decode 0 -> buf0 ----
    cwA = cbp[0];
    cwB = cbp[512];
    XISS(xwA); XISS(xwB);
    DECODE(cwA, 0);
    cwA = cbp[2 * 512];
    BARLDS();

    // ---- 64 steps, 2/iter ----
#pragma unroll 1
    for (int tt = 0; tt < 32; ++tt) {
        {   // even step s = 2tt : buf0, xwA
            short8 afr[2];
            AEXP(afr, xwA);
            if (tt < 31) XISS(xwA);
            BRDMFMA(afr, 0);
            DECODE(cwB, 1);                        // step 2tt+1 -> buf1
            if (tt < 31) cwB = cbp[(size_t)(2 * tt + 3) * 512];
            BARLDS();
        }
        {   // odd step s = 2tt+1 : buf1, xwB
            short8 afr[2];
            AEXP(afr, xwB);
            if (tt < 31) XISS(xwB);
            BRDMFMA(afr, 1);
            if (tt < 31) {
                DECODE(cwA, 0);                    // step 2tt+2 -> buf0
                if (tt < 30) cwA = cbp[(size_t)(2 * tt + 4) * 512];
                BARLDS();
            }
        }
    }

    // ---- colsum reduce + epilogue (exact: integers <= 2048) ----
    csl[wv][lane][0] = cs[0]; csl[wv][lane][1] = cs[1];
    csl[wv][lane][2] = cs[2]; csl[wv][lane][3] = cs[3];
    __syncthreads();

    float* obase = out + ((size_t)p * NB + h * 256 + wv * 32) * NO + og * OT;
#pragma unroll
    for (int nj = 0; nj < 16; ++nj) {
        const int colT = nj * 16 + lanelo;
        float csT = 0.0f;
#pragma unroll
        for (int q = 0; q < 8; ++q) csT += csl[q][colT >> 2][colT & 3];
#pragma unroll
        for (int mi = 0; mi < 2; ++mi) {
            const int r0 = mi * 16 + (lane >> 4) * 4;
            const f32x4 v = acc[mi][nj];
            obase[(size_t)(r0 + 0) * NO + colT] = v[0] + csT;
            obase[(size_t)(r0 + 1) * NO + colT] = v[1] + csT;
            obase[(size_t)(r0 + 2) * NO + colT] = v[2] + csT;
            obase[(size_t)(r0 + 3) * NO + colT] = v[3] + csT;
        }
    }
}

// ----------------------------------------------- fallback: R16 verbatim ----
__global__ __launch_bounds__(512, 2) void evo_w4(const float* __restrict__ w,
                                                 const uint32_t* __restrict__ xp,
                                                 float* __restrict__ out) {
    __shared__ __align__(16) uint16_t bds[2][OT][44];
    __shared__ float csl[8][64][4];

    const int tid    = threadIdx.x;
    const int lane   = tid & 63;
    const int wv     = __builtin_amdgcn_readfirstlane(tid >> 6);
    const int lanelo = lane & 15;
    const int klo8   = (lane >> 4) * 8;
    const int h      = blockIdx.x >> 7;
    const int t      = blockIdx.x & 127;
    const int p      = t >> 3;
    const int og     = t & 7;

    const size_t wq = (size_t)NI * NO;
    const float* w0n = w + (size_t)p * wq + (size_t)(4 * wv) * NO
                     + og * OT + 4 * lane;
    const float* w1n = w0n + (size_t)NP * wq;
    const uint32_t* xn = xp + ((size_t)p * NB + h * 256 + wv * 32 + lanelo) * JW;

    f32x4 acc[2][16];
#pragma unroll
    for (int mi = 0; mi < 2; ++mi)
#pragma unroll
        for (int nj = 0; nj < 16; ++nj) acc[mi][nj] = (f32x4)0.0f;
    float cs[4] = {0.0f, 0.0f, 0.0f, 0.0f};

    f32x4 wA0[4], wA1[4], wB0[4], wB1[4];
    uint32_t xwA[2], xwB[2];

    WISS(wA0, wA1);
    WISS(wB0, wB1);
    XISS(xwA); XISS(xwB);
    CVT(wA0, wA1, 0);
    WISS(wA0, wA1);
    BARLDS();

#pragma unroll 1
    for (int ss = 0; ss < 32; ++ss) {
        {
            short8 afr[2];
            AEXP(afr, xwA);
            if (ss < 31) XISS(xwA);
            BRDMFMA(afr, 0);
            CVT(wB0, wB1, 1);
            if (ss < 31) WISS(wB0, wB1);
            BARLDS();
        }
        {
            short8 afr[2];
            AEXP(afr, xwB);
            if (ss < 31) XISS(xwB);
            BRDMFMA(afr, 1);
            if (ss < 31) {
                CVT(wA0, wA1, 0);
                if (ss < 30) WISS(wA0, wA1);
                BARLDS();
            }
        }
    }

    csl[wv][lane][0] = cs[0]; csl[wv][lane][1] = cs[1];
    csl[wv][lane][2] = cs[2]; csl[wv][lane][3] = cs[3];
    __syncthreads();

    float* obase = out + ((size_t)p * NB + h * 256 + wv * 32) * NO + og * OT;
#pragma unroll
    for (int nj = 0; nj < 16; ++nj) {
        const int colT = nj * 16 + lanelo;
        float csT = 0.0f;
#pragma unroll
        for (int q = 0; q < 8; ++q) csT += csl[q][colT >> 2][colT & 3];
#pragma unroll
        for (int mi = 0; mi < 2; ++mi) {
            const int r0 = mi * 16 + (lane >> 4) * 4;
            const f32x4 v = acc[mi][nj];
            obase[(size_t)(r0 + 0) * NO + colT] = v[0] + csT;
            obase[(size_t)(r0 + 1) * NO + colT] = v[1] + csT;
            obase[(size_t)(r0 + 2) * NO + colT] = v[2] + csT;
            obase[(size_t)(r0 + 3) * NO + colT] = v[3] + csT;
        }
    }
}

// ---------------------------------------------------------------- launch ----
extern "C" void kernel_launch(void* const* d_in, const int* in_sizes, int n_in,
                              void* d_out, int out_size, void* d_ws, size_t ws_size,
                              hipStream_t stream) {
    const float* x = (const float*)d_in[0];   // (16,512,2048) fp32 {0,1}
    const float* w = (const float*)d_in[1];   // (2,16,1,2048,2048) fp32 {0,1}
    float* out     = (float*)d_out;           // (16,512,2048) fp32
    uint32_t* xp   = (uint32_t*)d_ws;         // 2 MiB packed x
    uint32_t* cb   = xp + XP_WORDS;           // 16 MiB packed w codes

    pack_x_kernel<<<dim3((NP * NB * 64) / 256), dim3(256), 0, stream>>>(x, xp);

    const size_t need = ((size_t)XP_WORDS + (size_t)128 * CBT) * 4;  // 18.87 MB
    if (ws_size >= need) {
        pack_w_kernel<<<dim3(NP * 512), dim3(256), 0, stream>>>(w, cb);
        evo_code<<<dim3(256), dim3(512), 0, stream>>>(cb, xp, out);
    } else {
        evo_w4<<<dim3(256), dim3(512), 0, stream>>>(w, xp, out);
    }
}

// Round 14
// 162.812 us; speedup vs baseline: 1.3930x; 1.3930x over previous
//
#include <hip/hip_runtime.h>
#include <stdint.h>

// out[p,b,o] = sum_i x*w0 + (1-x)*w1 = sum_i x*(w0-w1) + sum_i w1
// R22 == R16 (best measured: 162.6 us), restored verbatim after R17-R21
// exhausted the w-dedup search space (see session ledger). MFMA
// formulation: d = w0-w1 in {-1,0,1} (bf16-exact), x in {0,1}, fp32
// accumulation of integers <= 2048 -> EXACT.
//   Grid 256 = (tile t = 16p x 8og(256 cols)) x (h = b-half), 1 block/CU.
//   Block: 512 thr = 8 waves; wave wv owns b-rows h*256+wv*32..+31
//   (2 m-frags) x 256 cols (16 n-frags); acc[2][16] f32x4 = 128 VGPR.
//   Per step (32 k): wave wv loads k-rows 4wv..4wv+3, both mats, lane l
//   cols 4l..4l+3 (f32x4 = wave-wide 1024B strip -> ~max DRAM efficiency,
//   the R15->R16 lever); d=w0-w1 -> bf16 tile bds[col][44] (pitch 88B);
//   colsum(w1) per-thread. 2-step-deep w prefetch (dual reg sets);
//   lgkmcnt-only barriers (vmcnt FIFO never drained).

#define NP 16
#define NB 512
#define NI 2048
#define NO 2048
#define JW 64               // u32 words per i-row in xp
#define OT 256              // o-columns per block
#define KS 32               // k-rows per step
#define NST (NI / KS)       // 64 steps

typedef __attribute__((ext_vector_type(8))) short short8;
typedef __attribute__((ext_vector_type(4))) float f32x4;

__global__ __launch_bounds__(256) void pack_x_kernel(const float* __restrict__ x,
                                                     uint32_t* __restrict__ xp) {
    const int gtid = blockIdx.x * 256 + threadIdx.x;
    const int row  = gtid >> 6;     // p*NB + b
    const int lane = gtid & 63;
    const float* src = x + (size_t)row * NI;
    unsigned long long* dst = (unsigned long long*)(xp + (size_t)row * JW);
#pragma unroll 4
    for (int k = 0; k < NI / 64; ++k) {
        const float v = src[k * 64 + lane];
        const unsigned long long m = __ballot(v != 0.0f);
        if (lane == 0) dst[k] = m;
    }
}

// bf16 truncation (exact for d in {-1,0,1} and w1 in {0,1})
#define BF16(f) ((uint32_t)(__float_as_uint(f) >> 16))

// issue next step's w: k-rows 4wv..4wv+3, lane cols 4l..4l+3, both mats
#define WISS(s0_, s1_) do {                                                    \
    _Pragma("unroll")                                                          \
    for (int _j = 0; _j < 4; ++_j) {                                           \
        s0_[_j] = *(const f32x4*)(w0n + (size_t)_j * NO);                      \
        s1_[_j] = *(const f32x4*)(w1n + (size_t)_j * NO);                      \
    }                                                                          \
    w0n += (size_t)KS * NO; w1n += (size_t)KS * NO;                            \
} while (0)

// convert a w set -> bf16 d tile rows 4wv..+3 of bds[b_]; colsum(w1).
// One b64 write per col (4 consecutive k packed).
#define CVT(s0_, s1_, b_) do {                                                 \
    _Pragma("unroll")                                                          \
    for (int _c = 0; _c < 4; ++_c) {                                           \
        const float _d0 = s0_[0][_c] - s1_[0][_c];                             \
        const float _d1 = s0_[1][_c] - s1_[1][_c];                             \
        const float _d2 = s0_[2][_c] - s1_[2][_c];                             \
        const float _d3 = s0_[3][_c] - s1_[3][_c];                             \
        cs[_c] += s1_[0][_c] + s1_[1][_c] + s1_[2][_c] + s1_[3][_c];           \
        uint2 _st;                                                             \
        _st.x = BF16(_d0) | (BF16(_d1) << 16);                                 \
        _st.y = BF16(_d2) | (BF16(_d3) << 16);                                 \
        *(uint2*)&bds[b_][4 * lane + _c][4 * wv] = _st;                        \
    }                                                                          \
} while (0)

// issue next x words (2 m-frag rows' step-word) and bump
#define XISS(xw) do {                                                          \
    xw[0] = xn[0]; xw[1] = xn[1024];                                           \
    xn += 1;                                                                   \
} while (0)

// expand A-frags from packed-x words: bit -> bf16 {0,1}  (R14-verified)
#define AEXP(afr, xw) do {                                                     \
    _Pragma("unroll")                                                          \
    for (int _mi = 0; _mi < 2; ++_mi) {                                        \
        const uint32_t _by = (xw[_mi] >> klo8) & 0xFFu;                        \
        union { uint32_t u[4]; short8 s; } _cv;                                \
        _cv.u[0] = (_by & 1u   ? 0x3F80u : 0u) | (_by & 2u   ? 0x3F800000u : 0u); \
        _cv.u[1] = (_by & 4u   ? 0x3F80u : 0u) | (_by & 8u   ? 0x3F800000u : 0u); \
        _cv.u[2] = (_by & 16u  ? 0x3F80u : 0u) | (_by & 32u  ? 0x3F800000u : 0u); \
        _cv.u[3] = (_by & 64u  ? 0x3F80u : 0u) | (_by & 128u ? 0x3F800000u : 0u); \
        afr[_mi] = _cv.s;                                                      \
    }                                                                          \
} while (0)

// read B-frags from bds[b_] (two b64s each; pitch 88B -> ~2-way, free) + MFMA
#define BRDMFMA(afr, b_) do {                                                  \
    _Pragma("unroll")                                                          \
    for (int _nj = 0; _nj < 16; ++_nj) {                                       \
        union { uint2 q[2]; short8 s; } _u;                                    \
        _u.q[0] = *(const uint2*)&bds[b_][_nj * 16 + lanelo][klo8];            \
        _u.q[1] = *(const uint2*)&bds[b_][_nj * 16 + lanelo][klo8 + 4];        \
        _Pragma("unroll")                                                      \
        for (int _mi = 0; _mi < 2; ++_mi)                                      \
            acc[_mi][_nj] = __builtin_amdgcn_mfma_f32_16x16x32_bf16(           \
                afr[_mi], _u.s, acc[_mi][_nj], 0, 0, 0);                       \
    }                                                                          \
} while (0)

// lgkmcnt-only barrier: LDS visibility without draining the w vmcnt FIFO
#define BARLDS() asm volatile("s_waitcnt lgkmcnt(0)\n\ts_barrier" ::: "memory")

__global__ __launch_bounds__(512, 2) void evo_w4(const float* __restrict__ w,
                                                 const uint32_t* __restrict__ xp,
                                                 float* __restrict__ out) {
    __shared__ __align__(16) uint16_t bds[2][OT][44];  // 44 KB, dbuf d tile
    __shared__ float csl[8][64][4];                    // 8 KB, colsum partials

    const int tid    = threadIdx.x;
    const int lane   = tid & 63;
    const int wv     = __builtin_amdgcn_readfirstlane(tid >> 6);  // 0..7
    const int lanelo = lane & 15;
    const int klo8   = (lane >> 4) * 8;
    const int h      = blockIdx.x >> 7;         // b-half 0..1
    const int t      = blockIdx.x & 127;        // tile
    const int p      = t >> 3;                  // 0..15
    const int og     = t & 7;                   // 0..7

    const size_t wq = (size_t)NI * NO;
    const float* w0n = w + (size_t)p * wq + (size_t)(4 * wv) * NO
                     + og * OT + 4 * lane;
    const float* w1n = w0n + (size_t)NP * wq;
    const uint32_t* xn = xp + ((size_t)p * NB + h * 256 + wv * 32 + lanelo) * JW;

    f32x4 acc[2][16];
#pragma unroll
    for (int mi = 0; mi < 2; ++mi)
#pragma unroll
        for (int nj = 0; nj < 16; ++nj) acc[mi][nj] = (f32x4)0.0f;
    float cs[4] = {0.0f, 0.0f, 0.0f, 0.0f};

    f32x4 wA0[4], wA1[4], wB0[4], wB1[4];
    uint32_t xwA[2], xwB[2];

    // ---- prologue: w(0),w(1),x(0),x(1) in flight; cvt w(0)->buf0; w(2) ----
    WISS(wA0, wA1);               // w(0)
    WISS(wB0, wB1);               // w(1)
    XISS(xwA); XISS(xwB);         // x(0), x(1)
    CVT(wA0, wA1, 0);             // waits w(0) only
    WISS(wA0, wA1);               // w(2)
    BARLDS();

    // ---- 64 steps, 2/iter; w issue->cvt distance = 2 full steps ----
#pragma unroll 1
    for (int ss = 0; ss < 32; ++ss) {
        {   // even step s = 2ss : buf0, xwA
            short8 afr[2];
            AEXP(afr, xwA);
            if (ss < 31) XISS(xwA);            // x(2ss+2)
            BRDMFMA(afr, 0);
            CVT(wB0, wB1, 1);                  // w(2ss+1) -> buf1
            if (ss < 31) WISS(wB0, wB1);       // w(2ss+3)
            BARLDS();
        }
        {   // odd step s = 2ss+1 : buf1, xwB
            short8 afr[2];
            AEXP(afr, xwB);
            if (ss < 31) XISS(xwB);            // x(2ss+3)
            BRDMFMA(afr, 1);
            if (ss < 31) {
                CVT(wA0, wA1, 0);              // w(2ss+2) -> buf0
                if (ss < 30) WISS(wA0, wA1);   // w(2ss+4), last valid = w62
                BARLDS();
            }
        }
    }

    // ---- colsum reduce + epilogue (exact: integers <= 2048) ----
    csl[wv][lane][0] = cs[0]; csl[wv][lane][1] = cs[1];
    csl[wv][lane][2] = cs[2]; csl[wv][lane][3] = cs[3];
    __syncthreads();

    float* obase = out + ((size_t)p * NB + h * 256 + wv * 32) * NO + og * OT;
#pragma unroll
    for (int nj = 0; nj < 16; ++nj) {
        const int colT = nj * 16 + lanelo;
        float csT = 0.0f;
#pragma unroll
        for (int q = 0; q < 8; ++q) csT += csl[q][colT >> 2][colT & 3];
#pragma unroll
        for (int mi = 0; mi < 2; ++mi) {
            const int r0 = mi * 16 + (lane >> 4) * 4;
            const f32x4 v = acc[mi][nj];
            obase[(size_t)(r0 + 0) * NO + colT] = v[0] + csT;
            obase[(size_t)(r0 + 1) * NO + colT] = v[1] + csT;
            obase[(size_t)(r0 + 2) * NO + colT] = v[2] + csT;
            obase[(size_t)(r0 + 3) * NO + colT] = v[3] + csT;
        }
    }
}

extern "C" void kernel_launch(void* const* d_in, const int* in_sizes, int n_in,
                              void* d_out, int out_size, void* d_ws, size_t ws_size,
                              hipStream_t stream) {
    const float* x = (const float*)d_in[0];   // (16,512,2048) fp32 {0,1}
    const float* w = (const float*)d_in[1];   // (2,16,1,2048,2048) fp32 {0,1}
    float* out     = (float*)d_out;           // (16,512,2048) fp32
    uint32_t* xp   = (uint32_t*)d_ws;         // 2 MB packed x

    pack_x_kernel<<<dim3((NP * NB * 64) / 256), dim3(256), 0, stream>>>(x, xp);
    evo_w4<<<dim3(256), dim3(512), 0, stream>>>(w, xp, out);
}